// Round 16
// baseline (498.392 us; speedup 1.0000x reference)
//
#include <hip/hip_runtime.h>
#include <hip/hip_fp16.h>
#include <cstdint>
#include <cstddef>

// ---------------------------------------------------------------------------
// GraphAutoencoder: 2 x [4-head GATConv(128->128) -> concat -> Linear(512->128) -> ReLU]
// N=50000, E=800000 (+N self-loops). fp32 in/out.
// Head GEMM (K=128): fully LDS-resident A+B (32KB+32KB), ONE barrier, 4
//   barrier-free k-steps; fused scores. Bit-identical accumulation to r14.
//   (r15 bug fixed: staging loop j<8 — full 128B per thread-half staged.)
// Lin GEMMs (K=512): round-14 verified loop (runtime K, async-STAGE split).
// Aggregate: round-9 fp16 row gather (at gather floor), 4 nodes/block.
// ---------------------------------------------------------------------------

#define FDIM   128
#define HEADS  4
#define HCAT   512

typedef unsigned short u16;
typedef __attribute__((ext_vector_type(4))) float f32x4;
typedef __attribute__((ext_vector_type(8))) _Float16 f16x8;

__device__ __forceinline__ u16 f2h_bits(float f) {
    _Float16 h = (_Float16)f;
    return *(u16*)&h;
}

// ---------------- edge dtype detection + deg zero (merged) ------------------
__global__ void k_detect_zero(const void* ei, int E, int N, int* flag, int* deg) {
    int i = blockIdx.x * blockDim.x + threadIdx.x;
    if (i < N) deg[i] = 0;
    if (i == 0) {
        const long long* p = (const long long*)ei;
        int bad = 0;
        int n = E < 64 ? E : 64;
        for (int k = 0; k < n; ++k) {
            long long v = p[k];
            if (v < 0 || v >= (long long)N) bad = 1;
        }
        *flag = bad;  // 1 => int32, 0 => int64
    }
}

__device__ __forceinline__ int edge_at(const void* ei, int is32, long long pos) {
    return is32 ? ((const int*)ei)[pos] : (int)(((const long long*)ei)[pos]);
}

__global__ void k_count(const void* ei, const int* flag, int E, int N, int* deg) {
    int e = blockIdx.x * blockDim.x + threadIdx.x;
    int Etot = E + N;
    if (e >= Etot) return;
    int is32 = *flag;
    int dst = (e < E) ? edge_at(ei, is32, (long long)E + e) : (e - E);
    atomicAdd(&deg[dst], 1);
}

// ---------------- multi-block exclusive scan --------------------------------
#define SCAN_BLOCKS 256
#define SCAN_TPB    256

__global__ __launch_bounds__(SCAN_TPB) void k_scan1(const int* __restrict__ deg,
                                                    int* __restrict__ bsum, int N) {
    __shared__ int sdata[SCAN_TPB];
    int b = blockIdx.x;
    int chunk = (N + SCAN_BLOCKS - 1) / SCAN_BLOCKS;
    int start = b * chunk;
    int end = start + chunk;
    if (start > N) start = N;
    if (end > N) end = N;
    int s = 0;
    for (int i = start + threadIdx.x; i < end; i += SCAN_TPB) s += deg[i];
    sdata[threadIdx.x] = s;
    __syncthreads();
    for (int o = SCAN_TPB / 2; o; o >>= 1) {
        if (threadIdx.x < o) sdata[threadIdx.x] += sdata[threadIdx.x + o];
        __syncthreads();
    }
    if (threadIdx.x == 0) bsum[b] = sdata[0];
}

__global__ __launch_bounds__(SCAN_BLOCKS) void k_scan2(const int* __restrict__ bsum,
                                                       int* __restrict__ bbase,
                                                       int* __restrict__ off_last) {
    __shared__ int sdata[SCAN_BLOCKS];
    int t = threadIdx.x;
    sdata[t] = bsum[t];
    __syncthreads();
    for (int o = 1; o < SCAN_BLOCKS; o <<= 1) {
        int v = (t >= o) ? sdata[t - o] : 0;
        __syncthreads();
        sdata[t] += v;
        __syncthreads();
    }
    bbase[t] = (t == 0) ? 0 : sdata[t - 1];
    if (t == SCAN_BLOCKS - 1) *off_last = sdata[t];
}

__global__ __launch_bounds__(SCAN_TPB) void k_scan3(const int* __restrict__ deg,
                                                    const int* __restrict__ bbase,
                                                    int* __restrict__ off,
                                                    int* __restrict__ cur, int N) {
    __shared__ int sdata[SCAN_TPB];
    int b = blockIdx.x;
    int chunk = (N + SCAN_BLOCKS - 1) / SCAN_BLOCKS;
    int start = b * chunk;
    int end = start + chunk;
    if (start > N) start = N;
    if (end > N) end = N;
    int base = bbase[b];
    for (int i0 = start; i0 < end; i0 += SCAN_TPB) {
        int i = i0 + threadIdx.x;
        int v = (i < end) ? deg[i] : 0;
        sdata[threadIdx.x] = v;
        __syncthreads();
        for (int o = 1; o < SCAN_TPB; o <<= 1) {
            int u = (threadIdx.x >= o) ? sdata[threadIdx.x - o] : 0;
            __syncthreads();
            sdata[threadIdx.x] += u;
            __syncthreads();
        }
        if (i < end) {
            int excl = base + sdata[threadIdx.x] - v;
            off[i] = excl;
            cur[i] = excl;
        }
        base += sdata[SCAN_TPB - 1];
        __syncthreads();
    }
}

__global__ void k_fill(const void* ei, const int* flag, int E, int N, int* cur, int* csr) {
    int e = blockIdx.x * blockDim.x + threadIdx.x;
    int Etot = E + N;
    if (e >= Etot) return;
    int is32 = *flag;
    int src, dst;
    if (e < E) {
        src = edge_at(ei, is32, e);
        dst = edge_at(ei, is32, (long long)E + e);
    } else {
        src = e - E;
        dst = e - E;
    }
    int pos = atomicAdd(&cur[dst], 1);
    csr[pos] = src;
}

// ---------------- merged operand prep ---------------------------------------
__global__ void k_prep(const float* __restrict__ x, u16* __restrict__ xh, int Nf,
                       const float* __restrict__ encW, u16* __restrict__ eh,
                       const float* __restrict__ linW, u16* __restrict__ lh,
                       const float* __restrict__ decW, u16* __restrict__ dh,
                       const float* __restrict__ dlW, u16* __restrict__ dh2) {
    int i = blockIdx.x * blockDim.x + threadIdx.x;
    if (i < Nf) {
        xh[i] = f2h_bits(x[i]);
        return;
    }
    int j = i - Nf;
    const int WSZ = HEADS * FDIM * FDIM;
    const float* W;
    u16* hi;
    int K;
    if (j < WSZ)            { W = encW; hi = eh;  K = FDIM; }
    else if (j < 2 * WSZ)   { W = linW; hi = lh;  K = HCAT; j -= WSZ; }
    else if (j < 3 * WSZ)   { W = decW; hi = dh;  K = FDIM; j -= 2 * WSZ; }
    else if (j < 4 * WSZ)   { W = dlW;  hi = dh2; K = HCAT; j -= 3 * WSZ; }
    else return;
    int blk = j / (K * 128);
    int rem = j - blk * K * 128;
    int k = rem >> 7, col = rem & 127;
    hi[(size_t)blk * 128 * K + (size_t)col * K + k] = f2h_bits(W[j]);
}

// ---------------- head GEMM: K=128, fully LDS-resident, 1 barrier -----------
// C-tile 128x128 for head yb. A [M][128] fp16; Bt [(yb*128+col)][128] fp16.
// Stage A (32KB) + B-head (32KB) once (8+8 uint4/thread) -> barrier -> 4
// barrier-free k-steps of frag reads + 16 MFMA. Accumulation order identical
// to r14. Writes Hb=fp16 (scattered, r14 path) + fused scores.
__global__ __launch_bounds__(256) void k_headgemm(
    const u16* __restrict__ A,
    const u16* __restrict__ Bt,
    const float* __restrict__ asrc, const float* __restrict__ adst,
    u16* __restrict__ Hb,
    float* __restrict__ ssrc, float* __restrict__ sdst,
    int M)
{
    __shared__ alignas(16) char smem[65536];
    __shared__ float sred[512];
    const int ASH = 0, BSH = 32768;
    int tid = threadIdx.x;
    int bm0 = blockIdx.x * 128;
    int yb = blockIdx.y;

    int wid = tid >> 6, lane = tid & 63;
    int wr = wid >> 1, wc = wid & 1;
    int fr = lane & 15, g = lane >> 4;

    // ---- stage A and B fully (once): 8+8 uint4 per thread ----
    {
        int row = tid >> 1, half = tid & 1;
        bool ain = (bm0 + row) < M;
        const u16* ap = A + (size_t)(bm0 + row) * FDIM + half * 64;
        const u16* bp = Bt + ((size_t)yb * 128 + row) * FDIM + half * 64;
        int sw = (row & 7) << 4;
#pragma unroll
        for (int j = 0; j < 8; ++j) {
            uint4 va = ain ? *(const uint4*)(ap + j * 8) : make_uint4(0, 0, 0, 0);
            uint4 vb = *(const uint4*)(bp + j * 8);
            *(uint4*)(smem + ASH + ((row * 256 + half * 128 + j * 16) ^ sw)) = va;
            *(uint4*)(smem + BSH + ((row * 256 + half * 128 + j * 16) ^ sw)) = vb;
        }
    }
    __syncthreads();

    f32x4 acc[4][4] = {};
#pragma unroll
    for (int ks = 0; ks < 4; ++ks) {
        int kb = ks * 64 + g * 16;   // byte offset of this lane's 8 k-elems
        f16x8 af[4], bh[4];
#pragma unroll
        for (int mi = 0; mi < 4; ++mi) {
            int r = wr * 64 + mi * 16 + fr;
            af[mi] = *(f16x8*)(smem + ASH + ((r * 256 + kb) ^ ((r & 7) << 4)));
        }
#pragma unroll
        for (int nj = 0; nj < 4; ++nj) {
            int c = wc * 64 + nj * 16 + fr;
            bh[nj] = *(f16x8*)(smem + BSH + ((c * 256 + kb) ^ ((c & 7) << 4)));
        }
#pragma unroll
        for (int mi = 0; mi < 4; ++mi)
#pragma unroll
            for (int nj = 0; nj < 4; ++nj)
                acc[mi][nj] = __builtin_amdgcn_mfma_f32_16x16x32_f16(af[mi], bh[nj], acc[mi][nj], 0, 0, 0);
    }

    // ---- Hb stores (r14 scattered path) ----
#pragma unroll
    for (int mi = 0; mi < 4; ++mi) {
#pragma unroll
        for (int q = 0; q < 4; ++q) {
            int r = bm0 + wr * 64 + mi * 16 + g * 4 + q;
            if (r >= M) continue;
#pragma unroll
            for (int nj = 0; nj < 4; ++nj) {
                int c = wc * 64 + nj * 16 + fr;
                Hb[(size_t)r * HCAT + yb * 128 + c] = f2h_bits(acc[mi][nj][q]);
            }
        }
    }

    // ---- fused attention scores for head yb (r14 path) ----
    {
        float asv[4], adv[4];
        const float* app = asrc + yb * FDIM;
        const float* dpp = adst + yb * FDIM;
#pragma unroll
        for (int nj = 0; nj < 4; ++nj) {
            int c = wc * 64 + nj * 16 + fr;
            asv[nj] = app[c];
            adv[nj] = dpp[c];
        }
#pragma unroll
        for (int mi = 0; mi < 4; ++mi) {
#pragma unroll
            for (int q = 0; q < 4; ++q) {
                float ps = 0.f, pd = 0.f;
#pragma unroll
                for (int nj = 0; nj < 4; ++nj) {
                    ps += acc[mi][nj][q] * asv[nj];
                    pd += acc[mi][nj][q] * adv[nj];
                }
#pragma unroll
                for (int o = 1; o < 16; o <<= 1) {
                    ps += __shfl_xor(ps, o);
                    pd += __shfl_xor(pd, o);
                }
                if (fr == 0) {
                    int row128 = wr * 64 + mi * 16 + g * 4 + q;
                    sred[(row128 * 2 + wc) * 2 + 0] = ps;
                    sred[(row128 * 2 + wc) * 2 + 1] = pd;
                }
            }
        }
        __syncthreads();
        {
            int rg = tid >> 1;
            int which = tid & 1;
            int r = bm0 + rg;
            if (r < M) {
                float v = sred[(rg * 2 + 0) * 2 + which] + sred[(rg * 2 + 1) * 2 + which];
                float* dstp = which ? sdst : ssrc;
                dstp[(size_t)yb * M + r] = v;
            }
        }
    }
}

// ---------------- lin GEMM (round-14 verified loop, runtime K) --------------
// MODE 1 (enc lin): bias+relu -> fp16. MODE 2 (dec lin): bias+relu -> fp32.
template <int MODE>
__global__ __launch_bounds__(256) void k_gemm_f16(
    const u16* __restrict__ A, int lda,
    const u16* __restrict__ Bt,
    const float* __restrict__ bias,
    float* __restrict__ C, u16* __restrict__ Cb1,
    int ldc, int M, int K)
{
    __shared__ alignas(16) char smem[16384];
    const int ASH = 0, BHI = 8192;
    int tid = threadIdx.x;
    int bm0 = blockIdx.x * 128;

    int wid = tid >> 6, lane = tid & 63;
    int wr = wid >> 1, wc = wid & 1;
    int fr = lane & 15, g = lane >> 4;

    f32x4 acc[4][4] = {};

    int arow = tid >> 1, ahalf = tid & 1;
    bool ain = (bm0 + arow) < M;
    const u16* aptr = A + (size_t)(bm0 + arow) * lda + ahalf * 16;
    int bcol = tid & 127, bhalf = tid >> 7;
    const u16* bph = Bt + (size_t)bcol * K + bhalf * 16;

    int abase = arow * 64 + ahalf * 32;
    int asw = (arow & 7) << 4;
    int bbase = bcol * 64 + bhalf * 32;
    int bsw = (bcol & 7) << 4;

    uint4 va0, va1, vb0, vb1;
    if (ain) { va0 = *(const uint4*)(aptr); va1 = *(const uint4*)(aptr + 8); }
    else { va0 = make_uint4(0, 0, 0, 0); va1 = make_uint4(0, 0, 0, 0); }
    vb0 = *(const uint4*)(bph);
    vb1 = *(const uint4*)(bph + 8);

    for (int k0 = 0; k0 < K; k0 += 32) {
        *(uint4*)(smem + ASH + ((abase +  0) ^ asw)) = va0;
        *(uint4*)(smem + ASH + ((abase + 16) ^ asw)) = va1;
        *(uint4*)(smem + BHI + ((bbase +  0) ^ bsw)) = vb0;
        *(uint4*)(smem + BHI + ((bbase + 16) ^ bsw)) = vb1;

        __syncthreads();

        if (k0 + 32 < K) {
            int kn = k0 + 32;
            if (ain) { va0 = *(const uint4*)(aptr + kn); va1 = *(const uint4*)(aptr + kn + 8); }
            else { va0 = make_uint4(0, 0, 0, 0); va1 = make_uint4(0, 0, 0, 0); }
            vb0 = *(const uint4*)(bph + kn);
            vb1 = *(const uint4*)(bph + kn + 8);
        }

        f16x8 af[4], bh[4];
#pragma unroll
        for (int mi = 0; mi < 4; ++mi) {
            int r = wr * 64 + mi * 16 + fr;
            int off = (r * 64 + g * 16) ^ ((r & 7) << 4);
            af[mi] = *(f16x8*)(smem + ASH + off);
        }
#pragma unroll
        for (int nj = 0; nj < 4; ++nj) {
            int c = wc * 64 + nj * 16 + fr;
            int off = (c * 64 + g * 16) ^ ((c & 7) << 4);
            bh[nj] = *(f16x8*)(smem + BHI + off);
        }

#pragma unroll
        for (int mi = 0; mi < 4; ++mi)
#pragma unroll
            for (int nj = 0; nj < 4; ++nj)
                acc[mi][nj] = __builtin_amdgcn_mfma_f32_16x16x32_f16(af[mi], bh[nj], acc[mi][nj], 0, 0, 0);
        __syncthreads();
    }

#pragma unroll
    for (int mi = 0; mi < 4; ++mi) {
#pragma unroll
        for (int q = 0; q < 4; ++q) {
            int r = bm0 + wr * 64 + mi * 16 + g * 4 + q;
            if (r >= M) continue;
#pragma unroll
            for (int nj = 0; nj < 4; ++nj) {
                int c = wc * 64 + nj * 16 + fr;
                float v = acc[mi][nj][q];
                v += bias[c];
                v = fmaxf(v, 0.f);
                if (MODE == 1) {
                    Cb1[(size_t)r * ldc + c] = f2h_bits(v);
                } else {
                    C[(size_t)r * ldc + c] = v;
                }
            }
        }
    }
}

// ---------------- segment softmax + fp16 gather aggregate -------------------
// 4 nodes/block (1 wave each); wave-level code identical to round 9.
__global__ __launch_bounds__(256) void k_aggregate(
    const u16* __restrict__ Hb, const int* __restrict__ off,
    const int* __restrict__ csr, const float* __restrict__ ssrc,
    const float* __restrict__ sdst, const float* __restrict__ bvec,
    u16* __restrict__ Gh, int N) {
    int n = blockIdx.x * 4 + (threadIdx.x >> 6);
    if (n >= N) return;
    int lane = threadIdx.x & 63;
    int o0 = __builtin_amdgcn_readfirstlane(off[n]);
    int o1 = __builtin_amdgcn_readfirstlane(off[n + 1]);
    int h = lane >> 4;
    int col0 = lane * 8;
    float sdh = sdst[(size_t)h * N + n];
    const float* ssrc_h = ssrc + (size_t)h * N;
    float denom = 0.f;
    float acc[8] = {0.f, 0.f, 0.f, 0.f, 0.f, 0.f, 0.f, 0.f};

    auto body = [&](float ew, uint4 hv) {
        const __half2* hp = (const __half2*)&hv;
#pragma unroll
        for (int j = 0; j < 4; ++j) {
            float2 f = __half22float2(hp[j]);
            acc[2 * j]     += ew * f.x;
            acc[2 * j + 1] += ew * f.y;
        }
    };

    int i = o0;
    for (; i + 4 <= o1; i += 4) {
        int s0 = csr[i + 0], s1 = csr[i + 1], s2 = csr[i + 2], s3 = csr[i + 3];
        uint4 v0 = *(const uint4*)&Hb[(size_t)s0 * HCAT + col0];
        uint4 v1 = *(const uint4*)&Hb[(size_t)s1 * HCAT + col0];
        uint4 v2 = *(const uint4*)&Hb[(size_t)s2 * HCAT + col0];
        uint4 v3 = *(const uint4*)&Hb[(size_t)s3 * HCAT + col0];
        float e0 = ssrc_h[s0] + sdh, e1 = ssrc_h[s1] + sdh;
        float e2 = ssrc_h[s2] + sdh, e3 = ssrc_h[s3] + sdh;
        e0 = e0 >= 0.f ? e0 : 0.2f * e0;
        e1 = e1 >= 0.f ? e1 : 0.2f * e1;
        e2 = e2 >= 0.f ? e2 : 0.2f * e2;
        e3 = e3 >= 0.f ? e3 : 0.2f * e3;
        float w0 = __expf(e0), w1 = __expf(e1), w2 = __expf(e2), w3 = __expf(e3);
        denom += (w0 + w1) + (w2 + w3);
        body(w0, v0);
        body(w1, v1);
        body(w2, v2);
        body(w3, v3);
    }
    for (; i < o1; ++i) {
        int s = csr[i];
        uint4 v = *(const uint4*)&Hb[(size_t)s * HCAT + col0];
        float e = ssrc_h[s] + sdh;
        e = e >= 0.f ? e : 0.2f * e;
        float ew = __expf(e);
        denom += ew;
        body(ew, v);
    }

    float inv = 1.f / denom;
    u16 hs[8];
#pragma unroll
    for (int k = 0; k < 8; ++k) {
        int col = col0 + k;
        float v = acc[k] * inv + bvec[h * FDIM + (col & 127)];
        hs[k] = f2h_bits(v);
    }
    *(uint4*)&Gh[(size_t)n * HCAT + col0] = *(uint4*)hs;
}

// ---------------------------------------------------------------------------
extern "C" void kernel_launch(void* const* d_in, const int* in_sizes, int n_in,
                              void* d_out, int out_size, void* d_ws, size_t ws_size,
                              hipStream_t stream) {
    const float* x = (const float*)d_in[0];
    const void* ei = d_in[1];
    const float* encW = (const float*)d_in[2];
    const float* enc_asrc = (const float*)d_in[3];
    const float* enc_adst = (const float*)d_in[4];
    const float* enc_b = (const float*)d_in[5];
    const float* enc_linW = (const float*)d_in[6];
    const float* enc_linb = (const float*)d_in[7];
    const float* decW = (const float*)d_in[8];
    const float* dec_asrc = (const float*)d_in[9];
    const float* dec_adst = (const float*)d_in[10];
    const float* dec_b = (const float*)d_in[11];
    const float* dec_linW = (const float*)d_in[12];
    const float* dec_linb = (const float*)d_in[13];

    int N = in_sizes[0] / FDIM;
    int E = in_sizes[1] / 2;
    int Etot = E + N;

    char* w = (char*)d_ws;
    size_t o = 0;
    auto alloc = [&](size_t bytes) -> char* {
        char* p = w + o;
        o += (bytes + 255) & ~(size_t)255;
        return p;
    };
    int* flag = (int*)alloc(4);
    int* deg = (int*)alloc((size_t)N * 4);
    int* off = (int*)alloc((size_t)(N + 1) * 4);
    int* cur = (int*)alloc((size_t)N * 4);
    int* csr = (int*)alloc((size_t)Etot * 4);
    int* bsum = (int*)alloc(SCAN_BLOCKS * 4);
    int* bbase = (int*)alloc(SCAN_BLOCKS * 4);
    float* ssrc = (float*)alloc((size_t)HEADS * N * 4);
    float* sdst = (float*)alloc((size_t)HEADS * N * 4);
    u16* Gh = (u16*)alloc((size_t)N * HCAT * 2);
    u16* Hb = (u16*)alloc((size_t)N * HCAT * 2);
    u16* xh = (u16*)alloc((size_t)N * FDIM * 2);
    u16* X2h = (u16*)alloc((size_t)N * FDIM * 2);
    u16* encWt_h = (u16*)alloc((size_t)HEADS * FDIM * FDIM * 2);
    u16* linWt_h = (u16*)alloc((size_t)HCAT * FDIM * 2);
    u16* decWt_h = (u16*)alloc((size_t)HEADS * FDIM * FDIM * 2);
    u16* dlinWt_h = (u16*)alloc((size_t)HCAT * FDIM * 2);
    (void)ws_size;

    // CSR build
    k_detect_zero<<<(N + 255) / 256, 256, 0, stream>>>(ei, E, N, flag, deg);
    k_count<<<(Etot + 255) / 256, 256, 0, stream>>>(ei, flag, E, N, deg);
    k_scan1<<<SCAN_BLOCKS, SCAN_TPB, 0, stream>>>(deg, bsum, N);
    k_scan2<<<1, SCAN_BLOCKS, 0, stream>>>(bsum, bbase, off + N);
    k_scan3<<<SCAN_BLOCKS, SCAN_TPB, 0, stream>>>(deg, bbase, off, cur, N);
    k_fill<<<(Etot + 255) / 256, 256, 0, stream>>>(ei, flag, E, N, cur, csr);

    // merged operand prep (xh + 4 weight transposes)
    int Nf = N * FDIM;
    int prep_total = Nf + 4 * HEADS * FDIM * FDIM;
    k_prep<<<(prep_total + 255) / 256, 256, 0, stream>>>(
        x, xh, Nf,
        encW, encWt_h,
        enc_linW, linWt_h,
        decW, decWt_h,
        dec_linW, dlinWt_h);

    int mblocks = (N + 127) / 128;
    int aggblocks = (N + 3) / 4;

    // ---- encoder ----
    k_headgemm<<<dim3(mblocks, 4), 256, 0, stream>>>(
        xh, encWt_h, enc_asrc, enc_adst, Hb, ssrc, sdst, N);
    k_aggregate<<<aggblocks, 256, 0, stream>>>(Hb, off, csr, ssrc, sdst, enc_b, Gh, N);
    k_gemm_f16<1><<<dim3(mblocks, 1), 256, 0, stream>>>(
        Gh, HCAT, linWt_h, enc_linb, nullptr, X2h, FDIM, N, HCAT);

    // ---- decoder ----
    k_headgemm<<<dim3(mblocks, 4), 256, 0, stream>>>(
        X2h, decWt_h, dec_asrc, dec_adst, Hb, ssrc, sdst, N);
    k_aggregate<<<aggblocks, 256, 0, stream>>>(Hb, off, csr, ssrc, sdst, dec_b, Gh, N);
    k_gemm_f16<2><<<dim3(mblocks, 1), 256, 0, stream>>>(
        Gh, HCAT, dlinWt_h, dec_linb, (float*)d_out, nullptr, FDIM, N, HCAT);
}

// Round 17
// 490.747 us; speedup vs baseline: 1.0156x; 1.0156x over previous
//
#include <hip/hip_runtime.h>
#include <hip/hip_fp16.h>
#include <cstdint>
#include <cstddef>

// ---------------------------------------------------------------------------
// GraphAutoencoder: 2 x [4-head GATConv(128->128) -> concat -> Linear(512->128) -> ReLU]
// N=50000, E=800000 (+N self-loops). fp32 in/out.
// GEMMs: fp16 MFMA (round-14 verified, byte-exact). Scores fused in head GEMM.
// Aggregate: round-9 structure with UNROLL-8 edge pipeline (latency-bound fix:
//   FETCH is L3-served, VALUBusy 26%, occupancy 75% -> more MLP per wave).
// ---------------------------------------------------------------------------

#define FDIM   128
#define HEADS  4
#define HCAT   512

typedef unsigned short u16;
typedef __attribute__((ext_vector_type(4))) float f32x4;
typedef __attribute__((ext_vector_type(8))) _Float16 f16x8;

__device__ __forceinline__ u16 f2h_bits(float f) {
    _Float16 h = (_Float16)f;
    return *(u16*)&h;
}

// ---------------- edge dtype detection + deg zero (merged) ------------------
__global__ void k_detect_zero(const void* ei, int E, int N, int* flag, int* deg) {
    int i = blockIdx.x * blockDim.x + threadIdx.x;
    if (i < N) deg[i] = 0;
    if (i == 0) {
        const long long* p = (const long long*)ei;
        int bad = 0;
        int n = E < 64 ? E : 64;
        for (int k = 0; k < n; ++k) {
            long long v = p[k];
            if (v < 0 || v >= (long long)N) bad = 1;
        }
        *flag = bad;  // 1 => int32, 0 => int64
    }
}

__device__ __forceinline__ int edge_at(const void* ei, int is32, long long pos) {
    return is32 ? ((const int*)ei)[pos] : (int)(((const long long*)ei)[pos]);
}

__global__ void k_count(const void* ei, const int* flag, int E, int N, int* deg) {
    int e = blockIdx.x * blockDim.x + threadIdx.x;
    int Etot = E + N;
    if (e >= Etot) return;
    int is32 = *flag;
    int dst = (e < E) ? edge_at(ei, is32, (long long)E + e) : (e - E);
    atomicAdd(&deg[dst], 1);
}

// ---------------- multi-block exclusive scan --------------------------------
#define SCAN_BLOCKS 256
#define SCAN_TPB    256

__global__ __launch_bounds__(SCAN_TPB) void k_scan1(const int* __restrict__ deg,
                                                    int* __restrict__ bsum, int N) {
    __shared__ int sdata[SCAN_TPB];
    int b = blockIdx.x;
    int chunk = (N + SCAN_BLOCKS - 1) / SCAN_BLOCKS;
    int start = b * chunk;
    int end = start + chunk;
    if (start > N) start = N;
    if (end > N) end = N;
    int s = 0;
    for (int i = start + threadIdx.x; i < end; i += SCAN_TPB) s += deg[i];
    sdata[threadIdx.x] = s;
    __syncthreads();
    for (int o = SCAN_TPB / 2; o; o >>= 1) {
        if (threadIdx.x < o) sdata[threadIdx.x] += sdata[threadIdx.x + o];
        __syncthreads();
    }
    if (threadIdx.x == 0) bsum[b] = sdata[0];
}

__global__ __launch_bounds__(SCAN_BLOCKS) void k_scan2(const int* __restrict__ bsum,
                                                       int* __restrict__ bbase,
                                                       int* __restrict__ off_last) {
    __shared__ int sdata[SCAN_BLOCKS];
    int t = threadIdx.x;
    sdata[t] = bsum[t];
    __syncthreads();
    for (int o = 1; o < SCAN_BLOCKS; o <<= 1) {
        int v = (t >= o) ? sdata[t - o] : 0;
        __syncthreads();
        sdata[t] += v;
        __syncthreads();
    }
    bbase[t] = (t == 0) ? 0 : sdata[t - 1];
    if (t == SCAN_BLOCKS - 1) *off_last = sdata[t];
}

__global__ __launch_bounds__(SCAN_TPB) void k_scan3(const int* __restrict__ deg,
                                                    const int* __restrict__ bbase,
                                                    int* __restrict__ off,
                                                    int* __restrict__ cur, int N) {
    __shared__ int sdata[SCAN_TPB];
    int b = blockIdx.x;
    int chunk = (N + SCAN_BLOCKS - 1) / SCAN_BLOCKS;
    int start = b * chunk;
    int end = start + chunk;
    if (start > N) start = N;
    if (end > N) end = N;
    int base = bbase[b];
    for (int i0 = start; i0 < end; i0 += SCAN_TPB) {
        int i = i0 + threadIdx.x;
        int v = (i < end) ? deg[i] : 0;
        sdata[threadIdx.x] = v;
        __syncthreads();
        for (int o = 1; o < SCAN_TPB; o <<= 1) {
            int u = (threadIdx.x >= o) ? sdata[threadIdx.x - o] : 0;
            __syncthreads();
            sdata[threadIdx.x] += u;
            __syncthreads();
        }
        if (i < end) {
            int excl = base + sdata[threadIdx.x] - v;
            off[i] = excl;
            cur[i] = excl;
        }
        base += sdata[SCAN_TPB - 1];
        __syncthreads();
    }
}

__global__ void k_fill(const void* ei, const int* flag, int E, int N, int* cur, int* csr) {
    int e = blockIdx.x * blockDim.x + threadIdx.x;
    int Etot = E + N;
    if (e >= Etot) return;
    int is32 = *flag;
    int src, dst;
    if (e < E) {
        src = edge_at(ei, is32, e);
        dst = edge_at(ei, is32, (long long)E + e);
    } else {
        src = e - E;
        dst = e - E;
    }
    int pos = atomicAdd(&cur[dst], 1);
    csr[pos] = src;
}

// ---------------- merged operand prep ---------------------------------------
__global__ void k_prep(const float* __restrict__ x, u16* __restrict__ xh, int Nf,
                       const float* __restrict__ encW, u16* __restrict__ eh,
                       const float* __restrict__ linW, u16* __restrict__ lh,
                       const float* __restrict__ decW, u16* __restrict__ dh,
                       const float* __restrict__ dlW, u16* __restrict__ dh2) {
    int i = blockIdx.x * blockDim.x + threadIdx.x;
    if (i < Nf) {
        xh[i] = f2h_bits(x[i]);
        return;
    }
    int j = i - Nf;
    const int WSZ = HEADS * FDIM * FDIM;
    const float* W;
    u16* hi;
    int K;
    if (j < WSZ)            { W = encW; hi = eh;  K = FDIM; }
    else if (j < 2 * WSZ)   { W = linW; hi = lh;  K = HCAT; j -= WSZ; }
    else if (j < 3 * WSZ)   { W = decW; hi = dh;  K = FDIM; j -= 2 * WSZ; }
    else if (j < 4 * WSZ)   { W = dlW;  hi = dh2; K = HCAT; j -= 3 * WSZ; }
    else return;
    int blk = j / (K * 128);
    int rem = j - blk * K * 128;
    int k = rem >> 7, col = rem & 127;
    hi[(size_t)blk * 128 * K + (size_t)col * K + k] = f2h_bits(W[j]);
}

// ---------------- fp16 MFMA GEMM (round-14 verified, byte-exact) ------------
// MODE 0 (head GEMM): writes Hb=fp16 + fused scores ssrc/sdst[yb][row].
// MODE 1 (enc lin): bias+relu -> fp16. MODE 2 (dec lin): bias+relu -> fp32.
template <int MODE>
__global__ __launch_bounds__(256) void k_gemm_f16(
    const u16* __restrict__ A, int lda,
    const u16* __restrict__ Bt,
    const float* __restrict__ bias,
    const float* __restrict__ asrc, const float* __restrict__ adst,
    float* __restrict__ C, u16* __restrict__ Cb1,
    float* __restrict__ ssrc, float* __restrict__ sdst,
    int ldc, int M, int K)
{
    __shared__ alignas(16) char smem[16384];
    __shared__ float sred[512];
    const int ASH = 0, BHI = 8192;
    int tid = threadIdx.x;
    int bm0 = blockIdx.x * 128;
    int yb = blockIdx.y;

    int wid = tid >> 6, lane = tid & 63;
    int wr = wid >> 1, wc = wid & 1;
    int fr = lane & 15, g = lane >> 4;

    f32x4 acc[4][4] = {};

    int arow = tid >> 1, ahalf = tid & 1;
    bool ain = (bm0 + arow) < M;
    const u16* aptr = A + (size_t)(bm0 + arow) * lda + ahalf * 16;
    int bcol = tid & 127, bhalf = tid >> 7;
    const u16* bph = Bt + (size_t)yb * 128 * K + (size_t)bcol * K + bhalf * 16;

    int abase = arow * 64 + ahalf * 32;
    int asw = (arow & 7) << 4;
    int bbase = bcol * 64 + bhalf * 32;
    int bsw = (bcol & 7) << 4;

    // prologue: issue loads for tile 0
    uint4 va0, va1, vb0, vb1;
    if (ain) { va0 = *(const uint4*)(aptr); va1 = *(const uint4*)(aptr + 8); }
    else { va0 = make_uint4(0, 0, 0, 0); va1 = make_uint4(0, 0, 0, 0); }
    vb0 = *(const uint4*)(bph);
    vb1 = *(const uint4*)(bph + 8);

    for (int k0 = 0; k0 < K; k0 += 32) {
        // stage the already-loaded tile (vmcnt wait covered by prev MFMAs)
        *(uint4*)(smem + ASH + ((abase +  0) ^ asw)) = va0;
        *(uint4*)(smem + ASH + ((abase + 16) ^ asw)) = va1;
        *(uint4*)(smem + BHI + ((bbase +  0) ^ bsw)) = vb0;
        *(uint4*)(smem + BHI + ((bbase + 16) ^ bsw)) = vb1;

        __syncthreads();

        // issue next tile's loads now; consumed at next iteration's stage
        if (k0 + 32 < K) {
            int kn = k0 + 32;
            if (ain) { va0 = *(const uint4*)(aptr + kn); va1 = *(const uint4*)(aptr + kn + 8); }
            else { va0 = make_uint4(0, 0, 0, 0); va1 = make_uint4(0, 0, 0, 0); }
            vb0 = *(const uint4*)(bph + kn);
            vb1 = *(const uint4*)(bph + kn + 8);
        }

        f16x8 af[4], bh[4];
#pragma unroll
        for (int mi = 0; mi < 4; ++mi) {
            int r = wr * 64 + mi * 16 + fr;
            int off = (r * 64 + g * 16) ^ ((r & 7) << 4);
            af[mi] = *(f16x8*)(smem + ASH + off);
        }
#pragma unroll
        for (int nj = 0; nj < 4; ++nj) {
            int c = wc * 64 + nj * 16 + fr;
            int off = (c * 64 + g * 16) ^ ((c & 7) << 4);
            bh[nj] = *(f16x8*)(smem + BHI + off);
        }

#pragma unroll
        for (int mi = 0; mi < 4; ++mi)
#pragma unroll
            for (int nj = 0; nj < 4; ++nj)
                acc[mi][nj] = __builtin_amdgcn_mfma_f32_16x16x32_f16(af[mi], bh[nj], acc[mi][nj], 0, 0, 0);
        __syncthreads();
    }

    // ---- main output stores ----
#pragma unroll
    for (int mi = 0; mi < 4; ++mi) {
#pragma unroll
        for (int q = 0; q < 4; ++q) {
            int r = bm0 + wr * 64 + mi * 16 + g * 4 + q;
            if (r >= M) continue;
#pragma unroll
            for (int nj = 0; nj < 4; ++nj) {
                int c = wc * 64 + nj * 16 + fr;     // col within yb's 128
                float v = acc[mi][nj][q];
                if (MODE == 0) {
                    Cb1[(size_t)r * ldc + yb * 128 + c] = f2h_bits(v);
                } else if (MODE == 1) {
                    v += bias[c];
                    v = fmaxf(v, 0.f);
                    Cb1[(size_t)r * ldc + c] = f2h_bits(v);
                } else {
                    v += bias[c];
                    v = fmaxf(v, 0.f);
                    C[(size_t)r * ldc + c] = v;
                }
            }
        }
    }

    // ---- MODE 0: fused attention scores for head yb ----
    if (MODE == 0) {
        float asv[4], adv[4];
        const float* app = asrc + yb * FDIM;
        const float* dpp = adst + yb * FDIM;
#pragma unroll
        for (int nj = 0; nj < 4; ++nj) {
            int c = wc * 64 + nj * 16 + fr;
            asv[nj] = app[c];
            adv[nj] = dpp[c];
        }
#pragma unroll
        for (int mi = 0; mi < 4; ++mi) {
#pragma unroll
            for (int q = 0; q < 4; ++q) {
                float ps = 0.f, pd = 0.f;
#pragma unroll
                for (int nj = 0; nj < 4; ++nj) {
                    ps += acc[mi][nj][q] * asv[nj];
                    pd += acc[mi][nj][q] * adv[nj];
                }
#pragma unroll
                for (int o = 1; o < 16; o <<= 1) {
                    ps += __shfl_xor(ps, o);
                    pd += __shfl_xor(pd, o);
                }
                if (fr == 0) {
                    int row128 = wr * 64 + mi * 16 + g * 4 + q;
                    sred[(row128 * 2 + wc) * 2 + 0] = ps;
                    sred[(row128 * 2 + wc) * 2 + 1] = pd;
                }
            }
        }
        __syncthreads();
        {
            int rg = tid >> 1;          // 0..127
            int which = tid & 1;
            int r = bm0 + rg;
            if (r < M) {
                float v = sred[(rg * 2 + 0) * 2 + which] + sred[(rg * 2 + 1) * 2 + which];
                float* dstp = which ? sdst : ssrc;
                dstp[(size_t)yb * M + r] = v;
            }
        }
    }
}

// ---------------- segment softmax + fp16 gather aggregate (unroll-8) --------
// 1 wave/node. Lane l owns columns [8l, 8l+8) (head = l>>4). No max pass
// (scores O(1), exp safe in fp32). 8 edges in flight for latency hiding.
__global__ __launch_bounds__(64) void k_aggregate(
    const u16* __restrict__ Hb, const int* __restrict__ off,
    const int* __restrict__ csr, const float* __restrict__ ssrc,
    const float* __restrict__ sdst, const float* __restrict__ bvec,
    u16* __restrict__ Gh, int N) {
    int n = blockIdx.x;
    int lane = threadIdx.x;
    int o0 = __builtin_amdgcn_readfirstlane(off[n]);
    int o1 = __builtin_amdgcn_readfirstlane(off[n + 1]);
    int h = lane >> 4;
    int col0 = lane * 8;
    float sdh = sdst[(size_t)h * N + n];
    const float* ssrc_h = ssrc + (size_t)h * N;
    float denom = 0.f;
    float acc[8] = {0.f, 0.f, 0.f, 0.f, 0.f, 0.f, 0.f, 0.f};

    auto body = [&](float ew, uint4 hv) {
        const __half2* hp = (const __half2*)&hv;
#pragma unroll
        for (int j = 0; j < 4; ++j) {
            float2 f = __half22float2(hp[j]);
            acc[2 * j]     += ew * f.x;
            acc[2 * j + 1] += ew * f.y;
        }
    };

    int i = o0;
    for (; i + 8 <= o1; i += 8) {
        int s[8];
#pragma unroll
        for (int u = 0; u < 8; ++u) s[u] = csr[i + u];
        uint4 v[8];
#pragma unroll
        for (int u = 0; u < 8; ++u)
            v[u] = *(const uint4*)&Hb[(size_t)s[u] * HCAT + col0];
        float e[8];
#pragma unroll
        for (int u = 0; u < 8; ++u) e[u] = ssrc_h[s[u]] + sdh;
#pragma unroll
        for (int u = 0; u < 8; ++u) {
            float ee = e[u] >= 0.f ? e[u] : 0.2f * e[u];
            float ew = __expf(ee);
            denom += ew;
            body(ew, v[u]);
        }
    }
    for (; i < o1; ++i) {
        int s = csr[i];
        uint4 v = *(const uint4*)&Hb[(size_t)s * HCAT + col0];
        float e = ssrc_h[s] + sdh;
        e = e >= 0.f ? e : 0.2f * e;
        float ew = __expf(e);
        denom += ew;
        body(ew, v);
    }

    float inv = 1.f / denom;
    u16 hs[8];
#pragma unroll
    for (int k = 0; k < 8; ++k) {
        int col = col0 + k;
        float v = acc[k] * inv + bvec[h * FDIM + (col & 127)];
        hs[k] = f2h_bits(v);
    }
    *(uint4*)&Gh[(size_t)n * HCAT + col0] = *(uint4*)hs;
}

// ---------------------------------------------------------------------------
extern "C" void kernel_launch(void* const* d_in, const int* in_sizes, int n_in,
                              void* d_out, int out_size, void* d_ws, size_t ws_size,
                              hipStream_t stream) {
    const float* x = (const float*)d_in[0];
    const void* ei = d_in[1];
    const float* encW = (const float*)d_in[2];
    const float* enc_asrc = (const float*)d_in[3];
    const float* enc_adst = (const float*)d_in[4];
    const float* enc_b = (const float*)d_in[5];
    const float* enc_linW = (const float*)d_in[6];
    const float* enc_linb = (const float*)d_in[7];
    const float* decW = (const float*)d_in[8];
    const float* dec_asrc = (const float*)d_in[9];
    const float* dec_adst = (const float*)d_in[10];
    const float* dec_b = (const float*)d_in[11];
    const float* dec_linW = (const float*)d_in[12];
    const float* dec_linb = (const float*)d_in[13];

    int N = in_sizes[0] / FDIM;
    int E = in_sizes[1] / 2;
    int Etot = E + N;

    char* w = (char*)d_ws;
    size_t o = 0;
    auto alloc = [&](size_t bytes) -> char* {
        char* p = w + o;
        o += (bytes + 255) & ~(size_t)255;
        return p;
    };
    int* flag = (int*)alloc(4);
    int* deg = (int*)alloc((size_t)N * 4);
    int* off = (int*)alloc((size_t)(N + 1) * 4);
    int* cur = (int*)alloc((size_t)N * 4);
    int* csr = (int*)alloc((size_t)Etot * 4);
    int* bsum = (int*)alloc(SCAN_BLOCKS * 4);
    int* bbase = (int*)alloc(SCAN_BLOCKS * 4);
    float* ssrc = (float*)alloc((size_t)HEADS * N * 4);
    float* sdst = (float*)alloc((size_t)HEADS * N * 4);
    u16* Gh = (u16*)alloc((size_t)N * HCAT * 2);
    u16* Hb = (u16*)alloc((size_t)N * HCAT * 2);
    u16* xh = (u16*)alloc((size_t)N * FDIM * 2);
    u16* X2h = (u16*)alloc((size_t)N * FDIM * 2);
    u16* encWt_h = (u16*)alloc((size_t)HEADS * FDIM * FDIM * 2);
    u16* linWt_h = (u16*)alloc((size_t)HCAT * FDIM * 2);
    u16* decWt_h = (u16*)alloc((size_t)HEADS * FDIM * FDIM * 2);
    u16* dlinWt_h = (u16*)alloc((size_t)HCAT * FDIM * 2);
    (void)ws_size;

    // CSR build
    k_detect_zero<<<(N + 255) / 256, 256, 0, stream>>>(ei, E, N, flag, deg);
    k_count<<<(Etot + 255) / 256, 256, 0, stream>>>(ei, flag, E, N, deg);
    k_scan1<<<SCAN_BLOCKS, SCAN_TPB, 0, stream>>>(deg, bsum, N);
    k_scan2<<<1, SCAN_BLOCKS, 0, stream>>>(bsum, bbase, off + N);
    k_scan3<<<SCAN_BLOCKS, SCAN_TPB, 0, stream>>>(deg, bbase, off, cur, N);
    k_fill<<<(Etot + 255) / 256, 256, 0, stream>>>(ei, flag, E, N, cur, csr);

    // merged operand prep (xh + 4 weight transposes)
    int Nf = N * FDIM;
    int prep_total = Nf + 4 * HEADS * FDIM * FDIM;
    k_prep<<<(prep_total + 255) / 256, 256, 0, stream>>>(
        x, xh, Nf,
        encW, encWt_h,
        enc_linW, linWt_h,
        decW, decWt_h,
        dec_linW, dlinWt_h);

    int mblocks = (N + 127) / 128;

    // ---- encoder ----
    k_gemm_f16<0><<<dim3(mblocks, 4), 256, 0, stream>>>(
        xh, FDIM, encWt_h, nullptr, enc_asrc, enc_adst,
        nullptr, Hb, ssrc, sdst, HCAT, N, FDIM);
    k_aggregate<<<N, 64, 0, stream>>>(Hb, off, csr, ssrc, sdst, enc_b, Gh, N);
    k_gemm_f16<1><<<dim3(mblocks, 1), 256, 0, stream>>>(
        Gh, HCAT, linWt_h, enc_linb, nullptr, nullptr,
        nullptr, X2h, nullptr, nullptr, FDIM, N, HCAT);

    // ---- decoder ----
    k_gemm_f16<0><<<dim3(mblocks, 4), 256, 0, stream>>>(
        X2h, FDIM, decWt_h, nullptr, dec_asrc, dec_adst,
        nullptr, Hb, ssrc, sdst, HCAT, N, FDIM);
    k_aggregate<<<N, 64, 0, stream>>>(Hb, off, csr, ssrc, sdst, dec_b, Gh, N);
    k_gemm_f16<2><<<dim3(mblocks, 1), 256, 0, stream>>>(
        Gh, HCAT, dlinWt_h, dec_linb, nullptr, nullptr,
        (float*)d_out, nullptr, nullptr, nullptr, FDIM, N, HCAT);
}